// Round 3
// baseline (238.057 us; speedup 1.0000x reference)
//
#include <hip/hip_runtime.h>
#include <hip/hip_bf16.h>

// ---------------------------------------------------------------------------
// Binary CNN forward (eval):
//  conv3x3(sign(x), sign(W1)) + b1 -> maxpool2x2 -> BN -> hardtanh -> sign
//  -> xnor-popcount GEMM vs sign(W2) + b2 -> BN -> hardtanh
//  -> fp32 GEMM vs W3 + b3 -> log_softmax
//
// K is padded from 98 to 112 u64 words; pad words are 0 in BOTH operands so
// xor-popcount over the pad contributes 0 mismatches and dot = 6272 - 2*acc
// stays exact.
// ---------------------------------------------------------------------------

#define EPS 1e-5f
#define KW 112   // padded K in u64 words (98 real + 14 zero)

// ---------- Stage 1 (merged): conv+pool+BN sign pack  |  pack sign(W2) ------
__global__ __launch_bounds__(256) void stage1(
    const float* __restrict__ x, const float* __restrict__ W1,
    const float* __restrict__ b1, const float* __restrict__ g1,
    const float* __restrict__ be1, const float* __restrict__ m1,
    const float* __restrict__ v1, const float* __restrict__ W2,
    unsigned long long* __restrict__ Apack,
    unsigned long long* __restrict__ Bpack) {
  __shared__ float sx[30][30];   // zero-padded binarized image
  __shared__ float wsg[32][9];   // sign(W1)
  __shared__ float cA[32], cB[32];

  const int t = threadIdx.x;
  const int lane = t & 63, wave = t >> 6;

  if (blockIdx.x >= 4096) {
    // ---- pack sign(W2) rows ----
    const int row = blockIdx.x - 4096;
    const float* wr = W2 + (long)row * 6272;
    for (int it = 0; it < 25; it++) {
      int f = it * 256 + t;
      bool pred = (f < 6272) ? (wr[f] >= 0.f) : false;
      unsigned long long word = __ballot(pred);
      int wi = it * 4 + wave;
      if (lane == 0 && wi < 100) Bpack[(long)row * KW + wi] = word;
    }
    if (t < 12) Bpack[(long)row * KW + 100 + t] = 0ULL;
    return;
  }

  // ---- conv path ----
  const int b = blockIdx.x;
  for (int i = t; i < 900; i += 256) ((float*)sx)[i] = 0.f;
  __syncthreads();
  const float* xb = x + b * 784;
  for (int p = t; p < 784; p += 256) {
    float v = xb[p];
    sx[p / 28 + 1][p % 28 + 1] = (v >= 0.f) ? 1.f : -1.f;
  }
  for (int i = t; i < 288; i += 256) wsg[i / 9][i % 9] = (W1[i] >= 0.f) ? 1.f : -1.f;
  if (t < 32) {
    float sc = g1[t] * rsqrtf(v1[t] + EPS);
    cA[t] = sc;
    cB[t] = sc * (b1[t] - m1[t]) + be1[t];  // pred = cA*maxconv + cB >= 0
  }
  __syncthreads();

  for (int it = 0; it < 25; it++) {
    int f = it * 256 + t;  // flatten index c*196 + h*14 + w
    bool pred = false;
    if (f < 6272) {
      int c = f / 196;
      int pos = f - c * 196;
      int h = pos / 14, w = pos - h * 14;
      int i0 = 2 * h, j0 = 2 * w;      // j0 even -> float2 aligned
      float p[4][4];
#pragma unroll
      for (int ii = 0; ii < 4; ii++) {
        float2 lo = *(const float2*)&sx[i0 + ii][j0];
        float2 hi = *(const float2*)&sx[i0 + ii][j0 + 2];
        p[ii][0] = lo.x; p[ii][1] = lo.y; p[ii][2] = hi.x; p[ii][3] = hi.y;
      }
      float mx = -1e30f;
#pragma unroll
      for (int di = 0; di < 2; di++)
#pragma unroll
        for (int dj = 0; dj < 2; dj++) {
          float acc = 0.f;
#pragma unroll
          for (int kh = 0; kh < 3; kh++)
#pragma unroll
            for (int kw = 0; kw < 3; kw++)
              acc += p[di + kh][dj + kw] * wsg[c][kh * 3 + kw];
          mx = fmaxf(mx, acc);
        }
      pred = (cA[c] * mx + cB[c]) >= 0.f;
    }
    unsigned long long word = __ballot(pred);
    int wi = it * 4 + wave;
    if (lane == 0 && wi < 100) Apack[(long)b * KW + wi] = word;
  }
  if (t < 12) Apack[(long)b * KW + 100 + t] = 0ULL;
}

// ---------- XNOR-popcount GEMM 4096x2048 (K = 112 u64 words) + BN2 + clip ---
// BM=128 x BN=64 tile, 256 threads, 8x4 outputs/thread.
// LDS row stride 17 u64 (odd) -> conflict-free b64 reads; BKW=16 fully
// unrolled -> LDS reads use compile-time immediate offsets.
#define BM 128
#define BN 64
__global__ __launch_bounds__(256) void bin_gemm(
    const unsigned long long* __restrict__ Apack,
    const unsigned long long* __restrict__ Bpack,
    const float* __restrict__ b2, const float* __restrict__ g2,
    const float* __restrict__ be2, const float* __restrict__ m2,
    const float* __restrict__ v2, float* __restrict__ z) {
  __shared__ unsigned long long As[BM * 17];
  __shared__ unsigned long long Bs[BN * 17];
  const int t = threadIdx.x;
  const int tx = t & 15, ty = t >> 4;
  const int tileM = blockIdx.y * BM, tileN = blockIdx.x * BN;

  unsigned int acc[8][4] = {};
  for (int ko = 0; ko < KW; ko += 16) {
    for (int i = t; i < BM * 16; i += 256) {
      int r = i >> 4, k = i & 15;
      As[r * 17 + k] = Apack[(long)(tileM + r) * KW + ko + k];
    }
    for (int i = t; i < BN * 16; i += 256) {
      int r = i >> 4, k = i & 15;
      Bs[r * 17 + k] = Bpack[(long)(tileN + r) * KW + ko + k];
    }
    __syncthreads();
#pragma unroll
    for (int kk = 0; kk < 16; kk++) {
      uint2 a[8], b[4];
#pragma unroll
      for (int i = 0; i < 8; i++)
        a[i] = *(const uint2*)&As[(ty + 16 * i) * 17 + kk];
#pragma unroll
      for (int j = 0; j < 4; j++)
        b[j] = *(const uint2*)&Bs[(tx + 16 * j) * 17 + kk];
#pragma unroll
      for (int i = 0; i < 8; i++)
#pragma unroll
        for (int j = 0; j < 4; j++)
          acc[i][j] += __popc(a[i].x ^ b[j].x) + __popc(a[i].y ^ b[j].y);
    }
    __syncthreads();
  }

#pragma unroll
  for (int j = 0; j < 4; j++) {
    int col = tileN + tx + 16 * j;
    float sc = g2[col] * rsqrtf(v2[col] + EPS);
    float off = sc * (b2[col] - m2[col]) + be2[col];
#pragma unroll
    for (int i = 0; i < 8; i++) {
      int row = tileM + ty + 16 * i;
      float dot = (float)(6272 - 2 * (int)acc[i][j]);
      float bn = sc * dot + off;
      bn = fminf(1.f, fmaxf(-1.f, bn));
      z[(long)row * 2048 + col] = bn;
    }
  }
}

// ---------- Final fp32 linear (10 x 2048) + log_softmax --------------------
// W3 is only 80 KB and reused by every block -> read from global (L2).
__global__ __launch_bounds__(256) void final_k(
    const float* __restrict__ z, const float* __restrict__ W3,
    const float* __restrict__ b3, float* __restrict__ out) {
  __shared__ float logits_s[4][10];
  const int t = threadIdx.x;
  const int wave = t >> 6, lane = t & 63;
  const int row = blockIdx.x * 4 + wave;
  float zr[32];
#pragma unroll
  for (int i = 0; i < 32; i++) zr[i] = z[(long)row * 2048 + lane + 64 * i];
  for (int cls = 0; cls < 10; cls++) {
    const float* w3r = W3 + cls * 2048;
    float acc = 0.f;
#pragma unroll
    for (int i = 0; i < 32; i++) acc += zr[i] * w3r[lane + 64 * i];
#pragma unroll
    for (int off = 32; off; off >>= 1) acc += __shfl_xor(acc, off);
    if (lane == 0) logits_s[wave][cls] = acc + b3[cls];
  }
  __syncthreads();
  if (lane < 10) {
    float v = logits_s[wave][lane];
    float m = logits_s[wave][0];
#pragma unroll
    for (int j = 1; j < 10; j++) m = fmaxf(m, logits_s[wave][j]);
    float s = 0.f;
#pragma unroll
    for (int j = 0; j < 10; j++) s += expf(logits_s[wave][j] - m);
    out[(long)row * 10 + lane] = v - m - logf(s);
  }
}

// ---------------------------------------------------------------------------
extern "C" void kernel_launch(void* const* d_in, const int* in_sizes, int n_in,
                              void* d_out, int out_size, void* d_ws, size_t ws_size,
                              hipStream_t stream) {
  const float* x   = (const float*)d_in[0];
  const float* W1  = (const float*)d_in[1];
  const float* b1  = (const float*)d_in[2];
  const float* g1  = (const float*)d_in[3];
  const float* be1 = (const float*)d_in[4];
  const float* m1  = (const float*)d_in[5];
  const float* v1  = (const float*)d_in[6];
  const float* W2  = (const float*)d_in[7];
  const float* b2  = (const float*)d_in[8];
  const float* g2  = (const float*)d_in[9];
  const float* be2 = (const float*)d_in[10];
  const float* m2  = (const float*)d_in[11];
  const float* v2  = (const float*)d_in[12];
  const float* W3  = (const float*)d_in[13];
  const float* b3  = (const float*)d_in[14];

  char* ws = (char*)d_ws;
  unsigned long long* Apack = (unsigned long long*)ws;                 // 4096*112*8 = 3,670,016 B
  unsigned long long* Bpack = (unsigned long long*)(ws + 3670016);     // 2048*112*8 = 1,835,008 B
  float* z = (float*)(ws + 3670016 + 1835008);                         // 4096*2048*4 = 33,554,432 B

  stage1<<<4096 + 2048, 256, 0, stream>>>(x, W1, b1, g1, be1, m1, v1, W2, Apack, Bpack);
  bin_gemm<<<dim3(2048 / BN, 4096 / BM), 256, 0, stream>>>(Apack, Bpack, b2, g2, be2, m2, v2, z);
  final_k<<<1024, 256, 0, stream>>>(z, W3, b3, (float*)d_out);
}

// Round 4
// 149.452 us; speedup vs baseline: 1.5929x; 1.5929x over previous
//
#include <hip/hip_runtime.h>
#include <hip/hip_bf16.h>

// ---------------------------------------------------------------------------
// Binary CNN forward (eval):
//  conv3x3(sign(x), sign(W1)) + b1 -> maxpool2x2 -> BN -> hardtanh -> sign
//  -> (i8 MFMA GEMM vs sign(W2)) + b2 -> BN -> hardtanh
//  -> fused W3 projection (atomic partial sums) -> +b3, log_softmax
//
// Signs are materialized as int8 +1/-1; dot products are exact in i32 MFMA.
// K = 6272 = 24*256 + 128; the tail half-chunk is zero-filled in LDS on both
// operands (0*0 contributes nothing) so accumulation stays exact.
// ---------------------------------------------------------------------------

#define EPS 1e-5f

typedef int i32x4 __attribute__((ext_vector_type(4)));
typedef int i32x16 __attribute__((ext_vector_type(16)));

// ---------- Stage 1 (merged): conv+pool+BN sign -> A8 | sign(W2) -> B8 ------
__global__ __launch_bounds__(256) void stage1(
    const float* __restrict__ x, const float* __restrict__ W1,
    const float* __restrict__ b1, const float* __restrict__ g1,
    const float* __restrict__ be1, const float* __restrict__ m1,
    const float* __restrict__ v1, const float* __restrict__ W2,
    signed char* __restrict__ A8, signed char* __restrict__ B8) {
  const int t = threadIdx.x;

  if (blockIdx.x >= 4096) {
    // ---- pack sign(W2) rows as int8 ----
    const int row = blockIdx.x - 4096;
    const float* wr = W2 + (long)row * 6272;
    signed char* br = B8 + (long)row * 6272;
    for (int it = 0; it < 25; it++) {
      int f = it * 256 + t;
      if (f < 6272) br[f] = (wr[f] >= 0.f) ? (signed char)1 : (signed char)-1;
    }
    return;
  }

  // ---- conv path ----
  __shared__ float sx[30][30];   // zero-padded binarized image
  __shared__ float wsg[32][9];   // sign(W1)
  __shared__ float cA[32], cB[32];
  const int b = blockIdx.x;
  for (int i = t; i < 900; i += 256) ((float*)sx)[i] = 0.f;
  __syncthreads();
  const float* xb = x + b * 784;
  for (int p = t; p < 784; p += 256) {
    float v = xb[p];
    sx[p / 28 + 1][p % 28 + 1] = (v >= 0.f) ? 1.f : -1.f;
  }
  for (int i = t; i < 288; i += 256) wsg[i / 9][i % 9] = (W1[i] >= 0.f) ? 1.f : -1.f;
  if (t < 32) {
    float sc = g1[t] * rsqrtf(v1[t] + EPS);
    cA[t] = sc;
    cB[t] = sc * (b1[t] - m1[t]) + be1[t];  // pred = cA*maxconv + cB >= 0
  }
  __syncthreads();

  signed char* ar = A8 + (long)b * 6272;
  for (int it = 0; it < 25; it++) {
    int f = it * 256 + t;  // flatten index c*196 + h*14 + w
    if (f < 6272) {
      int c = f / 196;
      int pos = f - c * 196;
      int h = pos / 14, w = pos - h * 14;
      int i0 = 2 * h, j0 = 2 * w;  // j0 even -> float2 aligned
      float p[4][4];
#pragma unroll
      for (int ii = 0; ii < 4; ii++) {
        float2 lo = *(const float2*)&sx[i0 + ii][j0];
        float2 hi = *(const float2*)&sx[i0 + ii][j0 + 2];
        p[ii][0] = lo.x; p[ii][1] = lo.y; p[ii][2] = hi.x; p[ii][3] = hi.y;
      }
      float mx = -1e30f;
#pragma unroll
      for (int di = 0; di < 2; di++)
#pragma unroll
        for (int dj = 0; dj < 2; dj++) {
          float acc = 0.f;
#pragma unroll
          for (int kh = 0; kh < 3; kh++)
#pragma unroll
            for (int kw = 0; kw < 3; kw++)
              acc += p[di + kh][dj + kw] * wsg[c][kh * 3 + kw];
          mx = fmaxf(mx, acc);
        }
      bool pred = (cA[c] * mx + cB[c]) >= 0.f;
      ar[f] = pred ? (signed char)1 : (signed char)-1;
    }
  }
}

// ---------- i8 MFMA GEMM 4096x2048 (K=6272) + BN2 + clip + W3 partials ------
#define TM 128
#define TN 128
#define BKB 256
#define KCH 25

__global__ __launch_bounds__(256) void mm_i8(
    const signed char* __restrict__ A8, const signed char* __restrict__ B8,
    const float* __restrict__ b2, const float* __restrict__ g2,
    const float* __restrict__ be2, const float* __restrict__ m2,
    const float* __restrict__ v2, const float* __restrict__ W3,
    float* __restrict__ logits) {
  __shared__ char smem[71168];          // [0,32768) sA | [32768,65536) sB
  char* sA = smem;                      // later overlaid by zb[128][129] f32
  char* sB = smem + 32768;
  float* w3s = (float*)(smem + 66048);  // W3 chunk 10x128

  const int t = threadIdx.x;
  const int lane = t & 63, w = t >> 6;
  const int l31 = lane & 31, lh = lane >> 5;
  const int wr = w >> 1, wc = w & 1;
  const long tileM = (long)blockIdx.y * TM;
  const long tileN = (long)blockIdx.x * TN;

  for (int i = t; i < 1280; i += 256)
    w3s[i] = W3[(i >> 7) * 2048 + tileN + (i & 127)];

  i32x16 acc[2][2];
#pragma unroll
  for (int a = 0; a < 2; a++)
#pragma unroll
    for (int q = 0; q < 2; q++) acc[a][q] = (i32x16)0;

  for (int kc = 0; kc < KCH; kc++) {
    i32x4 ra[8], rb[8];
    const long kb = (long)kc * BKB;
#pragma unroll
    for (int p = 0; p < 8; p++) {
      int e = p * 256 + t;
      int r = e >> 4, sl = e & 15;
      bool valid = (kc < KCH - 1) || (sl < 8);   // tail chunk: only 128 B real
      i32x4 va = (i32x4)0, vb = (i32x4)0;
      if (valid) {
        va = *(const i32x4*)(A8 + (tileM + r) * 6272 + kb + sl * 16);
        vb = *(const i32x4*)(B8 + (tileN + r) * 6272 + kb + sl * 16);
      }
      ra[p] = va; rb[p] = vb;
    }
    __syncthreads();   // previous iteration's frag reads complete
#pragma unroll
    for (int p = 0; p < 8; p++) {
      int e = p * 256 + t;
      int r = e >> 4, sl = e & 15;
      int off = r * 256 + ((sl ^ (r & 15)) << 4);
      *(i32x4*)(sA + off) = ra[p];
      *(i32x4*)(sB + off) = rb[p];
    }
    __syncthreads();
#pragma unroll
    for (int ks = 0; ks < 8; ks++) {
      int slot = ks * 2 + lh;
      i32x4 af[2], bf[2];
#pragma unroll
      for (int mt = 0; mt < 2; mt++) {
        int r = wr * 64 + mt * 32 + l31;
        af[mt] = *(const i32x4*)(sA + r * 256 + ((slot ^ (r & 15)) << 4));
      }
#pragma unroll
      for (int nt = 0; nt < 2; nt++) {
        int r = wc * 64 + nt * 32 + l31;
        bf[nt] = *(const i32x4*)(sB + r * 256 + ((slot ^ (r & 15)) << 4));
      }
#pragma unroll
      for (int mt = 0; mt < 2; mt++)
#pragma unroll
        for (int nt = 0; nt < 2; nt++)
          acc[mt][nt] = __builtin_amdgcn_mfma_i32_32x32x32_i8(
              af[mt], bf[nt], acc[mt][nt], 0, 0, 0);
    }
  }
  __syncthreads();  // all frag reads done; smem may be overlaid

  // ---- epilogue: z = clip(BN2(dot)) into LDS, then 10-class partial dots ---
  float* zb = (float*)smem;  // [128][129] floats = 66048 B
#pragma unroll
  for (int mt = 0; mt < 2; mt++)
#pragma unroll
    for (int nt = 0; nt < 2; nt++) {
      int cl = wc * 64 + nt * 32 + l31;
      int col = (int)tileN + cl;
      float sc = g2[col] * rsqrtf(v2[col] + EPS);
      float off = sc * (b2[col] - m2[col]) + be2[col];
      int rbase = wr * 64 + mt * 32 + 4 * lh;
#pragma unroll
      for (int q = 0; q < 16; q++) {
        int rl = rbase + (q & 3) + 8 * (q >> 2);
        float zz = sc * (float)acc[mt][nt][q] + off;
        zz = fminf(1.f, fmaxf(-1.f, zz));
        zb[rl * 129 + cl] = zz;
      }
    }
  __syncthreads();

#pragma unroll
  for (int i = 0; i < 5; i++) {
    int task = t + i * 256;           // 1280 tasks = 128 rows x 10 classes
    int row = task / 10, cls = task - row * 10;
    float s = 0.f;
#pragma unroll 8
    for (int c = 0; c < 128; c++) s += zb[row * 129 + c] * w3s[cls * 128 + c];
    atomicAdd(&logits[(tileM + row) * 10 + cls], s);
  }
}

// ---------- +b3, log_softmax over logits[4096][10] -------------------------
__global__ __launch_bounds__(256) void lsm2(const float* __restrict__ logits,
                                            const float* __restrict__ b3,
                                            float* __restrict__ out) {
  int r = blockIdx.x * 256 + threadIdx.x;
  const float* lr = logits + r * 10;
  float v[10];
#pragma unroll
  for (int j = 0; j < 10; j++) v[j] = lr[j] + b3[j];
  float m = v[0];
#pragma unroll
  for (int j = 1; j < 10; j++) m = fmaxf(m, v[j]);
  float s = 0.f;
#pragma unroll
  for (int j = 0; j < 10; j++) s += expf(v[j] - m);
  float ls = logf(s);
#pragma unroll
  for (int j = 0; j < 10; j++) out[r * 10 + j] = v[j] - m - ls;
}

// ---------------------------------------------------------------------------
extern "C" void kernel_launch(void* const* d_in, const int* in_sizes, int n_in,
                              void* d_out, int out_size, void* d_ws, size_t ws_size,
                              hipStream_t stream) {
  const float* x   = (const float*)d_in[0];
  const float* W1  = (const float*)d_in[1];
  const float* b1  = (const float*)d_in[2];
  const float* g1  = (const float*)d_in[3];
  const float* be1 = (const float*)d_in[4];
  const float* m1  = (const float*)d_in[5];
  const float* v1  = (const float*)d_in[6];
  const float* W2  = (const float*)d_in[7];
  const float* b2  = (const float*)d_in[8];
  const float* g2  = (const float*)d_in[9];
  const float* be2 = (const float*)d_in[10];
  const float* m2  = (const float*)d_in[11];
  const float* v2  = (const float*)d_in[12];
  const float* W3  = (const float*)d_in[13];
  const float* b3  = (const float*)d_in[14];

  char* ws = (char*)d_ws;
  signed char* A8 = (signed char*)ws;                 // 4096*6272 = 25,690,112 B
  signed char* B8 = (signed char*)(ws + 25690112);    // 2048*6272 = 12,845,056 B
  float* logits = (float*)(ws + 38535168);            // 4096*10*4 = 163,840 B

  hipMemsetAsync(logits, 0, 4096 * 10 * sizeof(float), stream);
  stage1<<<4096 + 2048, 256, 0, stream>>>(x, W1, b1, g1, be1, m1, v1, W2, A8, B8);
  mm_i8<<<dim3(2048 / TN, 4096 / TM), 256, 0, stream>>>(A8, B8, b2, g2, be2, m2,
                                                        v2, W3, logits);
  lsm2<<<16, 256, 0, stream>>>(logits, b3, (float*)d_out);
}

// Round 5
// 128.134 us; speedup vs baseline: 1.8579x; 1.1664x over previous
//
#include <hip/hip_runtime.h>
#include <hip/hip_bf16.h>

// ---------------------------------------------------------------------------
// Binary CNN forward (eval):
//  conv3x3(sign(x), sign(W1)) + b1 -> maxpool2x2 -> BN -> hardtanh -> sign
//  -> (i8 MFMA GEMM vs sign(W2)) + b2 -> BN -> hardtanh
//  -> fused W3 projection (atomic partial sums) -> +b3, log_softmax
//
// Signs are int8 +1/-1; dots are exact in i32 MFMA. K = 6272 = 49 * 128, so
// BK=128 bytes divides exactly (no tail, no padding).
// mm_i8: 128x128 tile, 4 waves (64x64 each, 2x2 of 32x32x32_i8), LDS
// double-buffered via global_load_lds with pre-swizzled global source
// (linear LDS dest; XOR-swizzled ds_read -> conflict-free frag reads).
// ---------------------------------------------------------------------------

#define EPS 1e-5f

typedef int i32x4 __attribute__((ext_vector_type(4)));
typedef int i32x16 __attribute__((ext_vector_type(16)));

#define GLD_LDS(gsrc, ldst)                                                   \
  __builtin_amdgcn_global_load_lds(                                           \
      (const __attribute__((address_space(1))) void*)(gsrc),                  \
      (__attribute__((address_space(3))) void*)(ldst), 16, 0, 0)

// ---------- Stage 1 (merged): conv+pool+BN sign -> A8 | sign(W2) -> B8 ------
__global__ __launch_bounds__(256) void stage1(
    const float* __restrict__ x, const float* __restrict__ W1,
    const float* __restrict__ b1, const float* __restrict__ g1,
    const float* __restrict__ be1, const float* __restrict__ m1,
    const float* __restrict__ v1, const float* __restrict__ W2,
    signed char* __restrict__ A8, signed char* __restrict__ B8) {
  const int t = threadIdx.x;

  if (blockIdx.x >= 4096) {
    // ---- pack sign(W2) rows as int8 ----
    const int row = blockIdx.x - 4096;
    const float* wr = W2 + (long)row * 6272;
    signed char* br = B8 + (long)row * 6272;
    for (int it = 0; it < 25; it++) {
      int f = it * 256 + t;
      if (f < 6272) br[f] = (wr[f] >= 0.f) ? (signed char)1 : (signed char)-1;
    }
    return;
  }

  // ---- conv path ----
  __shared__ float sx[30][30];   // zero-padded binarized image
  __shared__ float wsg[32][9];   // sign(W1)
  __shared__ float cA[32], cB[32];
  const int b = blockIdx.x;
  for (int i = t; i < 900; i += 256) ((float*)sx)[i] = 0.f;
  __syncthreads();
  const float* xb = x + b * 784;
  for (int p = t; p < 784; p += 256) {
    float v = xb[p];
    sx[p / 28 + 1][p % 28 + 1] = (v >= 0.f) ? 1.f : -1.f;
  }
  for (int i = t; i < 288; i += 256) wsg[i / 9][i % 9] = (W1[i] >= 0.f) ? 1.f : -1.f;
  if (t < 32) {
    float sc = g1[t] * rsqrtf(v1[t] + EPS);
    cA[t] = sc;
    cB[t] = sc * (b1[t] - m1[t]) + be1[t];  // pred = cA*maxconv + cB >= 0
  }
  __syncthreads();

  signed char* ar = A8 + (long)b * 6272;
  for (int it = 0; it < 25; it++) {
    int f = it * 256 + t;  // flatten index c*196 + h*14 + w
    if (f < 6272) {
      int c = f / 196;
      int pos = f - c * 196;
      int h = pos / 14, w = pos - h * 14;
      int i0 = 2 * h, j0 = 2 * w;  // j0 even -> float2 aligned
      float p[4][4];
#pragma unroll
      for (int ii = 0; ii < 4; ii++) {
        float2 lo = *(const float2*)&sx[i0 + ii][j0];
        float2 hi = *(const float2*)&sx[i0 + ii][j0 + 2];
        p[ii][0] = lo.x; p[ii][1] = lo.y; p[ii][2] = hi.x; p[ii][3] = hi.y;
      }
      float mx = -1e30f;
#pragma unroll
      for (int di = 0; di < 2; di++)
#pragma unroll
        for (int dj = 0; dj < 2; dj++) {
          float acc = 0.f;
#pragma unroll
          for (int kh = 0; kh < 3; kh++)
#pragma unroll
            for (int kw = 0; kw < 3; kw++)
              acc += p[di + kh][dj + kw] * wsg[c][kh * 3 + kw];
          mx = fmaxf(mx, acc);
        }
      bool pred = (cA[c] * mx + cB[c]) >= 0.f;
      ar[f] = pred ? (signed char)1 : (signed char)-1;
    }
  }
}

// ---------- i8 MFMA GEMM 4096x2048 (K=6272) + BN2 + clip + W3 partials ------
#define TM 128
#define TN 128
#define BKB 128   // K bytes per chunk
#define NKC 49    // 6272 / 128

// LDS map:
//  [0,32768)   : buffer 0 (sA 16K | sB 16K)     (A/B tile: 128 rows x 128 B)
//  [32768,65536): buffer 1
//  [0,67584)   : epilogue overlay zb[128][132] f32
//  [67584,72864): w3s[10][132] f32
__global__ __launch_bounds__(256) void mm_i8(
    const signed char* __restrict__ A8, const signed char* __restrict__ B8,
    const float* __restrict__ b2, const float* __restrict__ g2,
    const float* __restrict__ be2, const float* __restrict__ m2,
    const float* __restrict__ v2, const float* __restrict__ W3,
    float* __restrict__ logits) {
  __shared__ char smem[72864];
  float* w3s = (float*)(smem + 67584);

  const int t = threadIdx.x;
  const int lane = t & 63, w = t >> 6;
  const int l31 = lane & 31, lh = lane >> 5;
  const int wr = w >> 1, wc = w & 1;

  // XCD-aware block swizzle: 512 blocks, 8 XCDs -> each XCD gets 64
  // consecutive swz = 4 M-panels x 16 N-panels (A working set 3.2MB < 4MB L2).
  const int bid = blockIdx.x;
  const int swz = (bid & 7) * 64 + (bid >> 3);
  const long tileM = (long)(swz >> 4) * TM;
  const long tileN = (long)(swz & 15) * TN;

  for (int i = t; i < 1320; i += 256) {
    int cls = i / 132, c = i - cls * 132;
    w3s[i] = (c < 128) ? W3[cls * 2048 + tileN + c] : 0.f;
  }

  // stage one 128x128B A-tile + B-tile into buffer `buf` for chunk kc.
  // LDS linear (r, sl): byte off = r*128 + sl*16.  LDS[r][sl] holds global
  // slot (sl ^ (r&7)) -> frag read for slot s uses LDS slot (s ^ (r&7)).
  // Each global_load_lds: wave-uniform LDS base, per-lane global src, 16B.
  auto stage = [&](int buf, int kc) {
    const int kb = kc * BKB;
    char* sAb = smem + buf * 32768;
    char* sBb = sAb + 16384;
#pragma unroll
    for (int i = 0; i < 4; i++) {
      int base = (w * 4 + i) * 1024;
      int o = base + lane * 16;
      int r = o >> 7, sl = (o >> 4) & 7;
      int goff = kb + ((sl ^ (r & 7)) << 4);
      GLD_LDS(A8 + (tileM + r) * 6272 + goff, sAb + base);
      GLD_LDS(B8 + (tileN + r) * 6272 + goff, sBb + base);
    }
  };

  i32x16 acc[2][2];
#pragma unroll
  for (int a = 0; a < 2; a++)
#pragma unroll
    for (int q = 0; q < 2; q++) acc[a][q] = (i32x16)0;

  stage(0, 0);
  __syncthreads();   // compiler drains vmcnt before s_barrier

  int cur = 0;
  for (int kc = 0; kc < NKC; kc++) {
    if (kc + 1 < NKC) stage(cur ^ 1, kc + 1);  // prefetch overlaps compute
    const char* sAb = smem + cur * 32768;
    const char* sBb = sAb + 16384;
#pragma unroll
    for (int ks = 0; ks < 4; ks++) {
      int slot = ks * 2 + lh;
      i32x4 af[2], bf[2];
#pragma unroll
      for (int mt = 0; mt < 2; mt++) {
        int r = wr * 64 + mt * 32 + l31;
        af[mt] = *(const i32x4*)(sAb + r * 128 + ((slot ^ (r & 7)) << 4));
      }
#pragma unroll
      for (int nt = 0; nt < 2; nt++) {
        int r = wc * 64 + nt * 32 + l31;
        bf[nt] = *(const i32x4*)(sBb + r * 128 + ((slot ^ (r & 7)) << 4));
      }
#pragma unroll
      for (int mt = 0; mt < 2; mt++)
#pragma unroll
        for (int nt = 0; nt < 2; nt++)
          acc[mt][nt] = __builtin_amdgcn_mfma_i32_32x32x32_i8(
              af[mt], bf[nt], acc[mt][nt], 0, 0, 0);
    }
    __syncthreads();   // drains this wave's DMA (vmcnt) + guards buffer swap
    cur ^= 1;
  }

  // ---- epilogue: z = clip(BN2(dot)) into LDS, then 10-class partial dots ---
  float* zb = (float*)smem;  // [128][132] f32 = 67584 B (overlays both buffers)
#pragma unroll
  for (int mt = 0; mt < 2; mt++)
#pragma unroll
    for (int nt = 0; nt < 2; nt++) {
      int cl = wc * 64 + nt * 32 + l31;
      int col = (int)tileN + cl;
      float sc = g2[col] * rsqrtf(v2[col] + EPS);
      float off = sc * (b2[col] - m2[col]) + be2[col];
      int rbase = wr * 64 + mt * 32 + 4 * lh;
#pragma unroll
      for (int q = 0; q < 16; q++) {
        int rl = rbase + (q & 3) + 8 * (q >> 2);
        float zz = sc * (float)acc[mt][nt][q] + off;
        zz = fminf(1.f, fmaxf(-1.f, zz));
        zb[rl * 132 + cl] = zz;
      }
    }
  __syncthreads();

#pragma unroll
  for (int i = 0; i < 5; i++) {
    int task = t + i * 256;           // 1280 tasks = 128 rows x 10 classes
    int row = task / 10, cls = task - row * 10;
    float s = 0.f;
#pragma unroll
    for (int c4 = 0; c4 < 32; c4++) {
      float4 zv = *(const float4*)&zb[row * 132 + c4 * 4];
      float4 wv = *(const float4*)&w3s[cls * 132 + c4 * 4];
      s += zv.x * wv.x + zv.y * wv.y + zv.z * wv.z + zv.w * wv.w;
    }
    atomicAdd(&logits[(tileM + row) * 10 + cls], s);
  }
}

// ---------- +b3, log_softmax over logits[4096][10] -------------------------
__global__ __launch_bounds__(256) void lsm2(const float* __restrict__ logits,
                                            const float* __restrict__ b3,
                                            float* __restrict__ out) {
  int r = blockIdx.x * 256 + threadIdx.x;
  const float* lr = logits + r * 10;
  float v[10];
#pragma unroll
  for (int j = 0; j < 10; j++) v[j] = lr[j] + b3[j];
  float m = v[0];
#pragma unroll
  for (int j = 1; j < 10; j++) m = fmaxf(m, v[j]);
  float s = 0.f;
#pragma unroll
  for (int j = 0; j < 10; j++) s += expf(v[j] - m);
  float ls = logf(s);
#pragma unroll
  for (int j = 0; j < 10; j++) out[r * 10 + j] = v[j] - m - ls;
}

// ---------------------------------------------------------------------------
extern "C" void kernel_launch(void* const* d_in, const int* in_sizes, int n_in,
                              void* d_out, int out_size, void* d_ws, size_t ws_size,
                              hipStream_t stream) {
  const float* x   = (const float*)d_in[0];
  const float* W1  = (const float*)d_in[1];
  const float* b1  = (const float*)d_in[2];
  const float* g1  = (const float*)d_in[3];
  const float* be1 = (const float*)d_in[4];
  const float* m1  = (const float*)d_in[5];
  const float* v1  = (const float*)d_in[6];
  const float* W2  = (const float*)d_in[7];
  const float* b2  = (const float*)d_in[8];
  const float* g2  = (const float*)d_in[9];
  const float* be2 = (const float*)d_in[10];
  const float* m2  = (const float*)d_in[11];
  const float* v2  = (const float*)d_in[12];
  const float* W3  = (const float*)d_in[13];
  const float* b3  = (const float*)d_in[14];

  char* ws = (char*)d_ws;
  signed char* A8 = (signed char*)ws;                 // 4096*6272 = 25,690,112 B
  signed char* B8 = (signed char*)(ws + 25690112);    // 2048*6272 = 12,845,056 B
  float* logits = (float*)(ws + 38535168);            // 4096*10*4 = 163,840 B

  hipMemsetAsync(logits, 0, 4096 * 10 * sizeof(float), stream);
  stage1<<<4096 + 2048, 256, 0, stream>>>(x, W1, b1, g1, be1, m1, v1, W2, A8, B8);
  mm_i8<<<512, 256, 0, stream>>>(A8, B8, b2, g2, be2, m2, v2, W3, logits);
  lsm2<<<16, 256, 0, stream>>>(logits, b3, (float*)d_out);
}

// Round 6
// 98.021 us; speedup vs baseline: 2.4286x; 1.3072x over previous
//
#include <hip/hip_runtime.h>
#include <hip/hip_bf16.h>

// ---------------------------------------------------------------------------
// Binary CNN forward (eval):
//  conv3x3(sign(x), sign(W1)) + b1 -> maxpool2x2 -> BN -> hardtanh -> sign
//  -> (i8 MFMA GEMM vs sign(W2)) + b2 -> BN -> hardtanh
//  -> fused W3 projection (atomic partial sums) -> +b3, log_softmax
//
// All sign arithmetic is exact integer math (i8 dot products / i32 MFMA).
// ---------------------------------------------------------------------------

#define EPS 1e-5f

typedef int i32x4 __attribute__((ext_vector_type(4)));
typedef int i32x16 __attribute__((ext_vector_type(16)));

#define GLD_LDS(gsrc, ldst)                                                   \
  __builtin_amdgcn_global_load_lds(                                           \
      (const __attribute__((address_space(1))) void*)(gsrc),                  \
      (__attribute__((address_space(3))) void*)(ldst), 16, 0, 0)

// v_dot4_i32_i8: 4-way i8 dot + i32 acc in one instruction
#if defined(__has_builtin)
#if __has_builtin(__builtin_amdgcn_sdot4)
#define SDOT4(a, b, c) __builtin_amdgcn_sdot4((int)(a), (int)(b), (c), false)
#endif
#endif
#ifndef SDOT4
static __device__ __forceinline__ int sdot4_fb(int a, int b, int c) {
#pragma unroll
  for (int k = 0; k < 4; k++)
    c += ((int)(signed char)(a >> (8 * k))) * ((int)(signed char)(b >> (8 * k)));
  return c;
}
#define SDOT4(a, b, c) sdot4_fb((int)(a), (int)(b), (c))
#endif

// ---------- Stage 1 (merged): conv+pool+BN sign -> A8 | sign(W2) -> B8 ------
// Conv path: one thread per pooled output position (196 of 256 threads).
// The 4x4 input patch is channel-independent: loaded once as packed +-1
// bytes (border = 0 = zero padding, exact under integer dot), then a
// 32-channel loop does 12 x v_dot4_i32_i8 per channel (3x3 taps + zero pad
// byte per window row).
__global__ __launch_bounds__(256) void stage1(
    const float* __restrict__ x, const float* __restrict__ W1,
    const float* __restrict__ b1, const float* __restrict__ g1,
    const float* __restrict__ be1, const float* __restrict__ m1,
    const float* __restrict__ v1, const float* __restrict__ W2,
    signed char* __restrict__ A8, signed char* __restrict__ B8) {
  const int t = threadIdx.x;

  if (blockIdx.x >= 4096) {
    // ---- pack sign(W2) rows as int8 ----
    const int row = blockIdx.x - 4096;
    const float* wr = W2 + (long)row * 6272;
    signed char* br = B8 + (long)row * 6272;
    for (int it = 0; it < 25; it++) {
      int f = it * 256 + t;
      if (f < 6272) br[f] = (wr[f] >= 0.f) ? (signed char)1 : (signed char)-1;
    }
    return;
  }

  // ---- conv path ----
  __shared__ signed char sxb[30 * 32];  // padded binarized image, bytes
  __shared__ int wdw[32][3][2];         // weight dwords: [c][kh][dj]
  __shared__ float cAB[32][2];          // {cA, cB} per channel

  const int b = blockIdx.x;
  for (int i = t; i < 240; i += 256) ((int*)sxb)[i] = 0;  // zero incl. border
  __syncthreads();

  const float* xb = x + b * 784;
  for (int p = t; p < 784; p += 256) {
    float v = xb[p];
    sxb[(p / 28 + 1) * 32 + (p % 28) + 1] = (v >= 0.f) ? (signed char)1
                                                       : (signed char)-1;
  }
  if (t < 96) {
    int c = t / 3, kh = t - c * 3;
    const float* wp = W1 + c * 9 + kh * 3;
    unsigned u0 = (wp[0] >= 0.f) ? 0x01u : 0xFFu;
    unsigned u1 = (wp[1] >= 0.f) ? 0x01u : 0xFFu;
    unsigned u2 = (wp[2] >= 0.f) ? 0x01u : 0xFFu;
    wdw[c][kh][0] = (int)((u2 << 16) | (u1 << 8) | u0);   // (w0,w1,w2,0)
    wdw[c][kh][1] = (int)((u2 << 24) | (u1 << 16) | (u0 << 8));  // (0,w0,w1,w2)
  }
  if (t < 32) {
    float sc = g1[t] * rsqrtf(v1[t] + EPS);
    cAB[t][0] = sc;
    cAB[t][1] = sc * (b1[t] - m1[t]) + be1[t];  // pred = cA*maxconv + cB >= 0
  }
  __syncthreads();

  if (t < 196) {
    const int h = t / 14, w = t - h * 14;
    const int i0 = 2 * h, j0 = 2 * w;
    const int base = j0 & ~3, sh = (j0 & 3) * 8;  // sh in {0,16}
    unsigned prow[4];
#pragma unroll
    for (int ii = 0; ii < 4; ii++) {
      const int* rp = (const int*)&sxb[(i0 + ii) * 32 + base];
      unsigned long long chunk =
          (unsigned)rp[0] | ((unsigned long long)(unsigned)rp[1] << 32);
      prow[ii] = (unsigned)(chunk >> sh);  // bytes j0..j0+3 of padded row
    }
    signed char* ar = A8 + (long)b * 6272 + t;
#pragma unroll 8
    for (int c = 0; c < 32; c++) {
      int w00 = wdw[c][0][0], w01 = wdw[c][0][1];
      int w10 = wdw[c][1][0], w11 = wdw[c][1][1];
      int w20 = wdw[c][2][0], w21 = wdw[c][2][1];
      int c00 = SDOT4(prow[0], w00, SDOT4(prow[1], w10, SDOT4(prow[2], w20, 0)));
      int c01 = SDOT4(prow[0], w01, SDOT4(prow[1], w11, SDOT4(prow[2], w21, 0)));
      int c10 = SDOT4(prow[1], w00, SDOT4(prow[2], w10, SDOT4(prow[3], w20, 0)));
      int c11 = SDOT4(prow[1], w01, SDOT4(prow[2], w11, SDOT4(prow[3], w21, 0)));
      int mx = max(max(c00, c01), max(c10, c11));
      float pred = cAB[c][0] * (float)mx + cAB[c][1];
      ar[c * 196] = (pred >= 0.f) ? (signed char)1 : (signed char)-1;
    }
  }
}

// ---------- i8 MFMA GEMM 4096x2048 (K=6272) + BN2 + clip + W3 partials ------
#define TM 128
#define TN 128
#define BKB 128   // K bytes per chunk
#define NKC 49    // 6272 / 128

// LDS map:
//  [0,32768)   : buffer 0 (sA 16K | sB 16K)     (A/B tile: 128 rows x 128 B)
//  [32768,65536): buffer 1
//  [0,67584)   : epilogue overlay zb[128][132] f32
//  [67584,72864): w3s[10][132] f32
__global__ __launch_bounds__(256) void mm_i8(
    const signed char* __restrict__ A8, const signed char* __restrict__ B8,
    const float* __restrict__ b2, const float* __restrict__ g2,
    const float* __restrict__ be2, const float* __restrict__ m2,
    const float* __restrict__ v2, const float* __restrict__ W3,
    float* __restrict__ logits) {
  __shared__ char smem[72864];
  float* w3s = (float*)(smem + 67584);

  const int t = threadIdx.x;
  const int lane = t & 63, w = t >> 6;
  const int l31 = lane & 31, lh = lane >> 5;
  const int wr = w >> 1, wc = w & 1;

  // XCD-aware block swizzle: 512 blocks, 8 XCDs -> each XCD gets 64
  // consecutive swz = 4 M-panels x 16 N-panels (A working set 3.2MB < 4MB L2).
  const int bid = blockIdx.x;
  const int swz = (bid & 7) * 64 + (bid >> 3);
  const long tileM = (long)(swz >> 4) * TM;
  const long tileN = (long)(swz & 15) * TN;

  for (int i = t; i < 1320; i += 256) {
    int cls = i / 132, c = i - cls * 132;
    w3s[i] = (c < 128) ? W3[cls * 2048 + tileN + c] : 0.f;
  }

  // stage one 128x128B A-tile + B-tile into buffer `buf` for chunk kc.
  // LDS linear (r, sl): byte off = r*128 + sl*16.  LDS[r][sl] holds global
  // slot (sl ^ (r&7)) -> frag read for slot s uses LDS slot (s ^ (r&7)).
  auto stage = [&](int buf, int kc) {
    const int kb = kc * BKB;
    char* sAb = smem + buf * 32768;
    char* sBb = sAb + 16384;
#pragma unroll
    for (int i = 0; i < 4; i++) {
      int base = (w * 4 + i) * 1024;
      int o = base + lane * 16;
      int r = o >> 7, sl = (o >> 4) & 7;
      int goff = kb + ((sl ^ (r & 7)) << 4);
      GLD_LDS(A8 + (tileM + r) * 6272 + goff, sAb + base);
      GLD_LDS(B8 + (tileN + r) * 6272 + goff, sBb + base);
    }
  };

  i32x16 acc[2][2];
#pragma unroll
  for (int a = 0; a < 2; a++)
#pragma unroll
    for (int q = 0; q < 2; q++) acc[a][q] = (i32x16)0;

  stage(0, 0);
  __syncthreads();   // compiler drains vmcnt before s_barrier

  int cur = 0;
  for (int kc = 0; kc < NKC; kc++) {
    if (kc + 1 < NKC) stage(cur ^ 1, kc + 1);  // prefetch overlaps compute
    const char* sAb = smem + cur * 32768;
    const char* sBb = sAb + 16384;
#pragma unroll
    for (int ks = 0; ks < 4; ks++) {
      int slot = ks * 2 + lh;
      i32x4 af[2], bf[2];
#pragma unroll
      for (int mt = 0; mt < 2; mt++) {
        int r = wr * 64 + mt * 32 + l31;
        af[mt] = *(const i32x4*)(sAb + r * 128 + ((slot ^ (r & 7)) << 4));
      }
#pragma unroll
      for (int nt = 0; nt < 2; nt++) {
        int r = wc * 64 + nt * 32 + l31;
        bf[nt] = *(const i32x4*)(sBb + r * 128 + ((slot ^ (r & 7)) << 4));
      }
#pragma unroll
      for (int mt = 0; mt < 2; mt++)
#pragma unroll
        for (int nt = 0; nt < 2; nt++)
          acc[mt][nt] = __builtin_amdgcn_mfma_i32_32x32x32_i8(
              af[mt], bf[nt], acc[mt][nt], 0, 0, 0);
    }
    __syncthreads();   // drains this wave's DMA (vmcnt) + guards buffer swap
    cur ^= 1;
  }

  // ---- epilogue: z = clip(BN2(dot)) into LDS, then 10-class partial dots ---
  float* zb = (float*)smem;  // [128][132] f32 = 67584 B (overlays both buffers)
#pragma unroll
  for (int mt = 0; mt < 2; mt++)
#pragma unroll
    for (int nt = 0; nt < 2; nt++) {
      int cl = wc * 64 + nt * 32 + l31;
      int col = (int)tileN + cl;
      float sc = g2[col] * rsqrtf(v2[col] + EPS);
      float off = sc * (b2[col] - m2[col]) + be2[col];
      int rbase = wr * 64 + mt * 32 + 4 * lh;
#pragma unroll
      for (int q = 0; q < 16; q++) {
        int rl = rbase + (q & 3) + 8 * (q >> 2);
        float zz = sc * (float)acc[mt][nt][q] + off;
        zz = fminf(1.f, fmaxf(-1.f, zz));
        zb[rl * 132 + cl] = zz;
      }
    }
  __syncthreads();

#pragma unroll
  for (int i = 0; i < 5; i++) {
    int task = t + i * 256;           // 1280 tasks = 128 rows x 10 classes
    int row = task / 10, cls = task - row * 10;
    float s = 0.f;
#pragma unroll
    for (int c4 = 0; c4 < 32; c4++) {
      float4 zv = *(const float4*)&zb[row * 132 + c4 * 4];
      float4 wv = *(const float4*)&w3s[cls * 132 + c4 * 4];
      s += zv.x * wv.x + zv.y * wv.y + zv.z * wv.z + zv.w * wv.w;
    }
    atomicAdd(&logits[(tileM + row) * 10 + cls], s);
  }
}

// ---------- +b3, log_softmax over logits[4096][10] -------------------------
__global__ __launch_bounds__(256) void lsm2(const float* __restrict__ logits,
                                            const float* __restrict__ b3,
                                            float* __restrict__ out) {
  int r = blockIdx.x * 256 + threadIdx.x;
  const float* lr = logits + r * 10;
  float v[10];
#pragma unroll
  for (int j = 0; j < 10; j++) v[j] = lr[j] + b3[j];
  float m = v[0];
#pragma unroll
  for (int j = 1; j < 10; j++) m = fmaxf(m, v[j]);
  float s = 0.f;
#pragma unroll
  for (int j = 0; j < 10; j++) s += expf(v[j] - m);
  float ls = logf(s);
#pragma unroll
  for (int j = 0; j < 10; j++) out[r * 10 + j] = v[j] - m - ls;
}

// ---------------------------------------------------------------------------
extern "C" void kernel_launch(void* const* d_in, const int* in_sizes, int n_in,
                              void* d_out, int out_size, void* d_ws, size_t ws_size,
                              hipStream_t stream) {
  const float* x   = (const float*)d_in[0];
  const float* W1  = (const float*)d_in[1];
  const float* b1  = (const float*)d_in[2];
  const float* g1  = (const float*)d_in[3];
  const float* be1 = (const float*)d_in[4];
  const float* m1  = (const float*)d_in[5];
  const float* v1  = (const float*)d_in[6];
  const float* W2  = (const float*)d_in[7];
  const float* b2  = (const float*)d_in[8];
  const float* g2  = (const float*)d_in[9];
  const float* be2 = (const float*)d_in[10];
  const float* m2  = (const float*)d_in[11];
  const float* v2  = (const float*)d_in[12];
  const float* W3  = (const float*)d_in[13];
  const float* b3  = (const float*)d_in[14];

  char* ws = (char*)d_ws;
  signed char* A8 = (signed char*)ws;                 // 4096*6272 = 25,690,112 B
  signed char* B8 = (signed char*)(ws + 25690112);    // 2048*6272 = 12,845,056 B
  float* logits = (float*)(ws + 38535168);            // 4096*10*4 = 163,840 B

  hipMemsetAsync(logits, 0, 4096 * 10 * sizeof(float), stream);
  stage1<<<4096 + 2048, 256, 0, stream>>>(x, W1, b1, g1, be1, m1, v1, W2, A8, B8);
  mm_i8<<<512, 256, 0, stream>>>(A8, B8, b2, g2, be2, m2, v2, W3, logits);
  lsm2<<<16, 256, 0, stream>>>(logits, b3, (float*)d_out);
}

// Round 7
// 97.559 us; speedup vs baseline: 2.4401x; 1.0047x over previous
//
#include <hip/hip_runtime.h>
#include <hip/hip_bf16.h>

// ---------------------------------------------------------------------------
// Binary CNN forward (eval):
//  conv3x3(sign(x), sign(W1)) + b1 -> maxpool2x2 -> BN -> hardtanh -> sign
//  -> (i8 MFMA GEMM vs sign(W2)) + b2 -> BN -> hardtanh
//  -> fused W3 projection (atomic partial sums) -> +b3, log_softmax
//
// All sign arithmetic is exact integer math (i8 dot products / i32 MFMA).
// mm_i8: 256x128 tile, 8 waves (64x64 each), triple-buffered LDS staged via
// global_load_lds 2 chunks ahead, counted s_waitcnt vmcnt(6) (T4), 2 phases
// per chunk with setprio around the MFMA cluster (T3/T5).
// ---------------------------------------------------------------------------

#define EPS 1e-5f

typedef int i32x4 __attribute__((ext_vector_type(4)));
typedef int i32x16 __attribute__((ext_vector_type(16)));

#define GLD_LDS(gsrc, ldst)                                                   \
  __builtin_amdgcn_global_load_lds(                                           \
      (const __attribute__((address_space(1))) void*)(gsrc),                  \
      (__attribute__((address_space(3))) void*)(ldst), 16, 0, 0)

// v_dot4_i32_i8: 4-way i8 dot + i32 acc in one instruction
#if defined(__has_builtin)
#if __has_builtin(__builtin_amdgcn_sdot4)
#define SDOT4(a, b, c) __builtin_amdgcn_sdot4((int)(a), (int)(b), (c), false)
#endif
#endif
#ifndef SDOT4
static __device__ __forceinline__ int sdot4_fb(int a, int b, int c) {
#pragma unroll
  for (int k = 0; k < 4; k++)
    c += ((int)(signed char)(a >> (8 * k))) * ((int)(signed char)(b >> (8 * k)));
  return c;
}
#define SDOT4(a, b, c) sdot4_fb((int)(a), (int)(b), (c))
#endif

// ---------- Stage 1 (merged): conv+pool+BN sign -> A8 | sign(W2) -> B8 ------
__global__ __launch_bounds__(256) void stage1(
    const float* __restrict__ x, const float* __restrict__ W1,
    const float* __restrict__ b1, const float* __restrict__ g1,
    const float* __restrict__ be1, const float* __restrict__ m1,
    const float* __restrict__ v1, const float* __restrict__ W2,
    signed char* __restrict__ A8, signed char* __restrict__ B8) {
  const int t = threadIdx.x;

  if (blockIdx.x >= 4096) {
    // ---- pack sign(W2) rows as int8 ----
    const int row = blockIdx.x - 4096;
    const float* wr = W2 + (long)row * 6272;
    signed char* br = B8 + (long)row * 6272;
    for (int it = 0; it < 25; it++) {
      int f = it * 256 + t;
      if (f < 6272) br[f] = (wr[f] >= 0.f) ? (signed char)1 : (signed char)-1;
    }
    return;
  }

  // ---- conv path ----
  __shared__ signed char sxb[30 * 32];  // padded binarized image, bytes
  __shared__ int wdw[32][3][2];         // weight dwords: [c][kh][dj]
  __shared__ float cAB[32][2];          // {cA, cB} per channel

  const int b = blockIdx.x;
  for (int i = t; i < 240; i += 256) ((int*)sxb)[i] = 0;  // zero incl. border
  __syncthreads();

  const float* xb = x + b * 784;
  for (int p = t; p < 784; p += 256) {
    float v = xb[p];
    sxb[(p / 28 + 1) * 32 + (p % 28) + 1] = (v >= 0.f) ? (signed char)1
                                                       : (signed char)-1;
  }
  if (t < 96) {
    int c = t / 3, kh = t - c * 3;
    const float* wp = W1 + c * 9 + kh * 3;
    unsigned u0 = (wp[0] >= 0.f) ? 0x01u : 0xFFu;
    unsigned u1 = (wp[1] >= 0.f) ? 0x01u : 0xFFu;
    unsigned u2 = (wp[2] >= 0.f) ? 0x01u : 0xFFu;
    wdw[c][kh][0] = (int)((u2 << 16) | (u1 << 8) | u0);   // (w0,w1,w2,0)
    wdw[c][kh][1] = (int)((u2 << 24) | (u1 << 16) | (u0 << 8));  // (0,w0,w1,w2)
  }
  if (t < 32) {
    float sc = g1[t] * rsqrtf(v1[t] + EPS);
    cAB[t][0] = sc;
    cAB[t][1] = sc * (b1[t] - m1[t]) + be1[t];  // pred = cA*maxconv + cB >= 0
  }
  __syncthreads();

  if (t < 196) {
    const int h = t / 14, w = t - h * 14;
    const int i0 = 2 * h, j0 = 2 * w;
    const int base = j0 & ~3, sh = (j0 & 3) * 8;  // sh in {0,16}
    unsigned prow[4];
#pragma unroll
    for (int ii = 0; ii < 4; ii++) {
      const int* rp = (const int*)&sxb[(i0 + ii) * 32 + base];
      unsigned long long chunk =
          (unsigned)rp[0] | ((unsigned long long)(unsigned)rp[1] << 32);
      prow[ii] = (unsigned)(chunk >> sh);  // bytes j0..j0+3 of padded row
    }
    signed char* ar = A8 + (long)b * 6272 + t;
#pragma unroll 8
    for (int c = 0; c < 32; c++) {
      int w00 = wdw[c][0][0], w01 = wdw[c][0][1];
      int w10 = wdw[c][1][0], w11 = wdw[c][1][1];
      int w20 = wdw[c][2][0], w21 = wdw[c][2][1];
      int c00 = SDOT4(prow[0], w00, SDOT4(prow[1], w10, SDOT4(prow[2], w20, 0)));
      int c01 = SDOT4(prow[0], w01, SDOT4(prow[1], w11, SDOT4(prow[2], w21, 0)));
      int c10 = SDOT4(prow[1], w00, SDOT4(prow[2], w10, SDOT4(prow[3], w20, 0)));
      int c11 = SDOT4(prow[1], w01, SDOT4(prow[2], w11, SDOT4(prow[3], w21, 0)));
      int mx = max(max(c00, c01), max(c10, c11));
      float pred = cAB[c][0] * (float)mx + cAB[c][1];
      ar[c * 196] = (pred >= 0.f) ? (signed char)1 : (signed char)-1;
    }
  }
}

// ---------- i8 MFMA GEMM 4096x2048 (K=6272) + BN2 + clip + W3 partials ------
// 256x128 tile, 512 threads (8 waves, 4Mx2N), wave tile 64x64 (2x2 of
// 32x32x32_i8). Triple-buffered LDS, global_load_lds staged 2 chunks ahead,
// counted vmcnt(6), raw s_barrier, setprio around MFMA clusters.
#define TM 256
#define TN 128
#define BKB 128        // K bytes per chunk
#define NKC 49         // 6272 / 128
#define ABYTES 32768   // A tile bytes per chunk (256 rows x 128 B)
#define CHUNKB 49152   // A + B per chunk (48 KB)

// LDS map:
//  [0, 147456)      : 3 chunk buffers (each: A 32K | B 16K)
//  [0, 67584)       : epilogue overlay zb[128][132] f32 (after main loop)
//  [147456, 152736) : w3s[10][132] f32
__global__ __launch_bounds__(512, 2) void mm_i8(
    const signed char* __restrict__ A8, const signed char* __restrict__ B8,
    const float* __restrict__ b2, const float* __restrict__ g2,
    const float* __restrict__ be2, const float* __restrict__ m2,
    const float* __restrict__ v2, const float* __restrict__ W3,
    float* __restrict__ logits) {
  __shared__ __align__(16) char smem[152736];
  float* w3s = (float*)(smem + 147456);

  const int t = threadIdx.x;
  const int lane = t & 63, wv = t >> 6;
  const int l31 = lane & 31, lh = lane >> 5;
  const int wr = wv >> 1, wc = wv & 1;   // wave grid 4M x 2N

  // XCD-aware swizzle: 256 blocks = 1/CU; each XCD gets 32 consecutive swz
  // = 2 M-panels x 16 N-panels (A slice 3.2 MB < 4 MB XCD L2).
  const int bid = blockIdx.x;
  const int swz = (bid & 7) * 32 + (bid >> 3);
  const long tileM = (long)(swz >> 4) * TM;
  const long tileN = (long)(swz & 15) * TN;

  for (int i = t; i < 1320; i += 512) {
    int cls = i / 132, c = i - cls * 132;
    w3s[i] = (c < 128) ? W3[cls * 2048 + tileN + c] : 0.f;
  }

  // Stage chunk kc into buffer buf: 6 wave-instructions (j=0..3 A, 4..5 B).
  // LDS linear (r, sl): off = r*128 + sl*16, holding global slot sl^(r&7)
  // (inverse-swizzled source; frag read applies the same XOR).
  auto stageJ = [&](int buf, int kc, int j0, int j1) {
    const int kb = kc * BKB;
    char* base = smem + buf * CHUNKB;
#pragma unroll
    for (int j = j0; j < j1; j++) {
      int o = j * 8192 + wv * 1024 + lane * 16;
      if (j < 4) {
        int r = o >> 7, sl = (o >> 4) & 7;
        GLD_LDS(A8 + (tileM + r) * 6272 + kb + ((sl ^ (r & 7)) << 4),
                base + j * 8192 + wv * 1024);
      } else {
        int o2 = o - ABYTES;
        int r = o2 >> 7, sl = (o2 >> 4) & 7;
        GLD_LDS(B8 + (tileN + r) * 6272 + kb + ((sl ^ (r & 7)) << 4),
                base + ABYTES + (j - 4) * 8192 + wv * 1024);
      }
    }
  };

  i32x16 acc[2][2];
#pragma unroll
  for (int a = 0; a < 2; a++)
#pragma unroll
    for (int q = 0; q < 2; q++) acc[a][q] = (i32x16)0;

  // prologue: stage chunks 0 and 1
  stageJ(0, 0, 0, 6);
  stageJ(1, 1, 0, 6);

  int cur = 0;
  for (int kc = 0; kc < NKC; kc++) {
    // counted wait: newest 6 outstanding = chunk kc+1's loads; everything
    // older (chunk kc, staged 2 chunks ago) is complete. Last chunk: drain.
    if (kc == NKC - 1)
      asm volatile("s_waitcnt vmcnt(0)" ::: "memory");
    else
      asm volatile("s_waitcnt vmcnt(6)" ::: "memory");
    __builtin_amdgcn_s_barrier();

    const char* sAb = smem + cur * CHUNKB;
    const char* sBb = sAb + ABYTES;
    const int nbuf = (cur >= 1) ? cur - 1 : cur + 2;  // (cur+2)%3
    const bool dostage = (kc + 2 < NKC);

#pragma unroll
    for (int ph = 0; ph < 2; ph++) {
      i32x4 af[2][2], bf[2][2];  // [ks-in-phase][tile]
#pragma unroll
      for (int ksp = 0; ksp < 2; ksp++) {
        const int slot = (ph * 2 + ksp) * 2 + lh;
#pragma unroll
        for (int mt = 0; mt < 2; mt++) {
          int r = wr * 64 + mt * 32 + l31;
          af[ksp][mt] = *(const i32x4*)(sAb + r * 128 + ((slot ^ (r & 7)) << 4));
        }
#pragma unroll
        for (int nt = 0; nt < 2; nt++) {
          int r = wc * 64 + nt * 32 + l31;
          bf[ksp][nt] = *(const i32x4*)(sBb + r * 128 + ((slot ^ (r & 7)) << 4));
        }
      }
      if (dostage) stageJ(nbuf, kc + 2, ph * 3, ph * 3 + 3);
      __builtin_amdgcn_s_setprio(1);
#pragma unroll
      for (int ksp = 0; ksp < 2; ksp++)
#pragma unroll
        for (int mt = 0; mt < 2; mt++)
#pragma unroll
          for (int nt = 0; nt < 2; nt++)
            acc[mt][nt] = __builtin_amdgcn_mfma_i32_32x32x32_i8(
                af[ksp][mt], bf[ksp][nt], acc[mt][nt], 0, 0, 0);
      __builtin_amdgcn_s_setprio(0);
      if (ph == 0) __builtin_amdgcn_s_barrier();
    }
    cur = (cur >= 2) ? 0 : cur + 1;
  }
  __builtin_amdgcn_s_barrier();  // all frag reads done; smem may be overlaid

  // ---- epilogue: two 128-row passes; z = clip(BN2(dot)) -> LDS -> W3 dots --
  float* zb = (float*)smem;  // [128][132] f32 = 67584 B
#pragma unroll
  for (int pass = 0; pass < 2; pass++) {
    if ((wr >> 1) == pass) {  // waves wr in {2*pass, 2*pass+1}
#pragma unroll
      for (int mt = 0; mt < 2; mt++)
#pragma unroll
        for (int nt = 0; nt < 2; nt++) {
          int cl = wc * 64 + nt * 32 + l31;
          int col = (int)tileN + cl;
          float sc = g2[col] * rsqrtf(v2[col] + EPS);
          float off = sc * (b2[col] - m2[col]) + be2[col];
          int rbase = (wr & 1) * 64 + mt * 32 + 4 * lh;
#pragma unroll
          for (int q = 0; q < 16; q++) {
            int rl = rbase + (q & 3) + 8 * (q >> 2);
            float zz = sc * (float)acc[mt][nt][q] + off;
            zz = fminf(1.f, fmaxf(-1.f, zz));
            zb[rl * 132 + cl] = zz;
          }
        }
    }
    __builtin_amdgcn_s_barrier();

#pragma unroll
    for (int i = 0; i < 3; i++) {
      int task = t + i * 512;  // 1280 tasks = 128 rows x 10 classes
      if (task < 1280) {
        int row = task / 10, cls = task - row * 10;
        float s = 0.f;
#pragma unroll
        for (int c4 = 0; c4 < 32; c4++) {
          float4 zv = *(const float4*)&zb[row * 132 + c4 * 4];
          float4 wv4 = *(const float4*)&w3s[cls * 132 + c4 * 4];
          s += zv.x * wv4.x + zv.y * wv4.y + zv.z * wv4.z + zv.w * wv4.w;
        }
        atomicAdd(&logits[(tileM + pass * 128 + row) * 10 + cls], s);
      }
    }
    __builtin_amdgcn_s_barrier();
  }
}

// ---------- +b3, log_softmax over logits[4096][10] -------------------------
__global__ __launch_bounds__(256) void lsm2(const float* __restrict__ logits,
                                            const float* __restrict__ b3,
                                            float* __restrict__ out) {
  int r = blockIdx.x * 256 + threadIdx.x;
  const float* lr = logits + r * 10;
  float v[10];
#pragma unroll
  for (int j = 0; j < 10; j++) v[j] = lr[j] + b3[j];
  float m = v[0];
#pragma unroll
  for (int j = 1; j < 10; j++) m = fmaxf(m, v[j]);
  float s = 0.f;
#pragma unroll
  for (int j = 0; j < 10; j++) s += expf(v[j] - m);
  float ls = logf(s);
#pragma unroll
  for (int j = 0; j < 10; j++) out[r * 10 + j] = v[j] - m - ls;
}

// ---------------------------------------------------------------------------
extern "C" void kernel_launch(void* const* d_in, const int* in_sizes, int n_in,
                              void* d_out, int out_size, void* d_ws, size_t ws_size,
                              hipStream_t stream) {
  const float* x   = (const float*)d_in[0];
  const float* W1  = (const float*)d_in[1];
  const float* b1  = (const float*)d_in[2];
  const float* g1  = (const float*)d_in[3];
  const float* be1 = (const float*)d_in[4];
  const float* m1  = (const float*)d_in[5];
  const float* v1  = (const float*)d_in[6];
  const float* W2  = (const float*)d_in[7];
  const float* b2  = (const float*)d_in[8];
  const float* g2  = (const float*)d_in[9];
  const float* be2 = (const float*)d_in[10];
  const float* m2  = (const float*)d_in[11];
  const float* v2  = (const float*)d_in[12];
  const float* W3  = (const float*)d_in[13];
  const float* b3  = (const float*)d_in[14];

  char* ws = (char*)d_ws;
  signed char* A8 = (signed char*)ws;                 // 4096*6272 = 25,690,112 B
  signed char* B8 = (signed char*)(ws + 25690112);    // 2048*6272 = 12,845,056 B
  float* logits = (float*)(ws + 38535168);            // 4096*10*4 = 163,840 B

  hipMemsetAsync(logits, 0, 4096 * 10 * sizeof(float), stream);
  stage1<<<4096 + 2048, 256, 0, stream>>>(x, W1, b1, g1, be1, m1, v1, W2, A8, B8);
  mm_i8<<<256, 512, 0, stream>>>(A8, B8, b2, g2, be2, m2, v2, W3, logits);
  lsm2<<<16, 256, 0, stream>>>(logits, b3, (float*)d_out);
}